// Round 8
// baseline (171.037 us; speedup 1.0000x reference)
//
#include <hip/hip_runtime.h>
#include <hip/hip_bf16.h>
#include <cstddef>

// ---------------- problem constants (match reference) ----------------
constexpr int N      = 50000;
constexpr int E      = 1600000;
constexpr int NFEAT  = 256;
constexpr float SLOPE = 0.2f;
constexpr float L1d  = 0.5f;
constexpr float L2d  = 0.5f;

// ---------------- counting-sort CSR parameters ----------------
constexpr int BSHIFT = 7;                         // 128 nodes per bucket
constexpr int NBUK   = (N + 127) >> BSHIFT;       // 391 buckets
constexpr int EPB    = 4096;                      // edges per block (P1/P2)
constexpr int NBLK   = (E + EPB - 1) / EPB;       // 391 blocks
constexpr int CAP    = 5120;                      // LDS stage capacity

// ---------------- workspace layout (units of 4 bytes) ----------------
constexpr size_t al64(size_t x) { return (x + 63) & ~size_t(63); }
constexpr size_t W_OFFS  = 0;                            // int[N+1]
constexpr size_t W_CSR   = W_OFFS  + al64(N + 1);        // int[E]
constexpr size_t W_STAGE = W_CSR   + (size_t)E;          // uint[E]
constexpr size_t W_BHIST = W_STAGE + (size_t)E;          // int[NBLK*NBUK]
constexpr size_t W_TOT   = W_BHIST + al64((size_t)NBLK * NBUK);  // int[NBUK]
constexpr size_t W_BBASE = W_TOT   + al64(NBUK);         // int[NBUK+1]
constexpr size_t W_H1B   = W_BBASE + al64(NBUK + 1);     // bf16[N*64] -> N*32 words
constexpr size_t W_S1B   = W_H1B   + (size_t)N * 32;     // bf16[N*8]  -> N*4
constexpr size_t W_D1    = W_S1B   + (size_t)N * 4;      // f32[N*8]
constexpr size_t W_SIDE1 = W_D1    + (size_t)N * 8;      // f32[N*8]
constexpr size_t W_HF    = W_SIDE1 + (size_t)N * 8;      // f32[N*64]
constexpr size_t W_H2B   = W_HF    + (size_t)N * 64;     // bf16[N*16] -> N*8
constexpr size_t W_SIDE2 = W_H2B   + (size_t)N * 8;      // f32[N*16]
constexpr size_t W_S2B   = W_SIDE2 + (size_t)N * 16;     // bf16[N] -> N/2
constexpr size_t W_D2    = W_S2B   + al64(N / 2);        // f32[N]

typedef short bf16x8 __attribute__((ext_vector_type(8)));
typedef float f32x4  __attribute__((ext_vector_type(4)));

__device__ inline short f2bf(float f) {
    unsigned u = __builtin_bit_cast(unsigned, f);
    u += 0x7FFF + ((u >> 16) & 1);          // RNE
    return (short)(u >> 16);
}

__device__ inline float bfu2f(unsigned short u) {
    return __builtin_bit_cast(float, (unsigned)u << 16);
}

// broadcast value from lane ((lane & 0x18) | JJ) of each 8-lane group (imm pattern)
#define SWZ8(x, PAT) __builtin_bit_cast(float, __builtin_amdgcn_ds_swizzle(__builtin_bit_cast(int, (x)), (PAT)))

// =================== CSR build: two-level counting sort ===================

__global__ __launch_bounds__(256) void p1_hist_kernel(const int* __restrict__ ei,
                                                      int* __restrict__ bhist) {
    __shared__ int hist[NBUK];
    int tid = threadIdx.x;
    for (int j = tid; j < NBUK; j += 256) hist[j] = 0;
    __syncthreads();
    int base = blockIdx.x * EPB;
    int end = base + EPB; if (end > E) end = E;
    for (int i = base + tid; i < end; i += 256) {
        int d = ei[E + i];
        atomicAdd(&hist[d >> BSHIFT], 1);
    }
    __syncthreads();
    for (int j = tid; j < NBUK; j += 256) bhist[(size_t)blockIdx.x * NBUK + j] = hist[j];
}

__global__ __launch_bounds__(512) void s1_scan_kernel(int* __restrict__ bhist,
                                                      int* __restrict__ tot) {
    __shared__ int sd[512];
    int tid = threadIdx.x;
    int b = blockIdx.x;
    int v = (tid < NBLK) ? bhist[(size_t)tid * NBUK + b] : 0;
    sd[tid] = v;
    __syncthreads();
    for (int off = 1; off < 512; off <<= 1) {
        int t = (tid >= off) ? sd[tid - off] : 0;
        __syncthreads();
        sd[tid] += t;
        __syncthreads();
    }
    if (tid < NBLK) bhist[(size_t)tid * NBUK + b] = sd[tid] - v;
    if (tid == 511) tot[b] = sd[511];
}

__global__ __launch_bounds__(512) void s2_scan_kernel(const int* __restrict__ tot,
                                                      int* __restrict__ bbase,
                                                      int* __restrict__ offs) {
    __shared__ int sd[512];
    int tid = threadIdx.x;
    int v = (tid < NBUK) ? tot[tid] : 0;
    sd[tid] = v;
    __syncthreads();
    for (int off = 1; off < 512; off <<= 1) {
        int t = (tid >= off) ? sd[tid - off] : 0;
        __syncthreads();
        sd[tid] += t;
        __syncthreads();
    }
    if (tid < NBUK) bbase[tid] = sd[tid] - v;
    if (tid == 0) { bbase[NBUK] = E; offs[N] = E; }
}

__global__ __launch_bounds__(256) void p2_stage_kernel(const int* __restrict__ ei,
                                                       const int* __restrict__ bhist,
                                                       const int* __restrict__ bbase,
                                                       unsigned int* __restrict__ stage) {
    __shared__ int cur[NBUK];
    int tid = threadIdx.x;
    for (int j = tid; j < NBUK; j += 256)
        cur[j] = bbase[j] + bhist[(size_t)blockIdx.x * NBUK + j];
    __syncthreads();
    int base = blockIdx.x * EPB;
    int end = base + EPB; if (end > E) end = E;
    for (int i = base + tid; i < end; i += 256) {
        int s = ei[i];
        int d = ei[E + i];
        int b = d >> BSHIFT;
        int pos = atomicAdd(&cur[b], 1);
        stage[pos] = ((unsigned int)(d & 127) << 24) | (unsigned int)s;
    }
}

__global__ __launch_bounds__(256) void p3_fine_kernel(const unsigned int* __restrict__ stage,
                                                      const int* __restrict__ bbase,
                                                      int* __restrict__ offs,
                                                      int* __restrict__ csr) {
    __shared__ unsigned int sstage[CAP];
    __shared__ int hist[128];
    __shared__ int scn[128];
    __shared__ int cur[128];
    int tid = threadIdx.x;
    int b = blockIdx.x;
    int ebase = bbase[b], eend = bbase[b + 1];
    int cnt = eend - ebase;
    if (tid < 128) hist[tid] = 0;
    __syncthreads();
    for (int i = tid; i < cnt; i += 256) {
        unsigned int p = stage[ebase + i];
        if (i < CAP) sstage[i] = p;
        atomicAdd(&hist[p >> 24], 1);
    }
    __syncthreads();
    if (tid < 128) scn[tid] = hist[tid];
    __syncthreads();
    for (int off = 1; off < 128; off <<= 1) {
        int t = (tid < 128 && tid >= off) ? scn[tid - off] : 0;
        __syncthreads();
        if (tid < 128) scn[tid] += t;
        __syncthreads();
    }
    if (tid < 128) {
        int excl = scn[tid] - hist[tid];
        cur[tid] = excl;
        int v = (b << BSHIFT) + tid;
        if (v < N) offs[v] = ebase + excl;
    }
    __syncthreads();
    for (int i = tid; i < cnt; i += 256) {
        unsigned int p = (i < CAP) ? sstage[i] : stage[ebase + i];
        int dloc = (int)(p >> 24);
        int s = (int)(p & 0xFFFFFFu);
        int r = atomicAdd(&cur[dloc], 1);
        csr[ebase + r] = s;
    }
}

// ---------------- GEMM1 (MFMA bf16): [h1b | side1] = x @ [W1 | fc1W] ------------
__global__ __launch_bounds__(256) void gemm1_kernel(const float* __restrict__ x,
                                                    const float* __restrict__ W1,
                                                    const float* __restrict__ fc1W,
                                                    const float* __restrict__ fc1b,
                                                    short* __restrict__ h1b,
                                                    float* __restrict__ side1) {
    __shared__ bf16x8 wfrag[2560];   // 8 kt * 5 nt * 64 lanes * 16B = 40 KB
    int tid = threadIdx.x;

    for (int s = tid; s < 2560; s += 256) {
        int l = s & 63;
        int t = s >> 6;           // kt*5 + nt
        int nt = t % 5, kt = t / 5;
        int col = nt * 16 + (l & 15);
        int kbase = kt * 32 + (l >> 4) * 8;
        bf16x8 v;
#pragma unroll
        for (int j = 0; j < 8; ++j) {
            float f = 0.f;
            if (col < 64)      f = W1[(size_t)(kbase + j) * 64 + col];
            else if (col < 72) f = fc1W[(size_t)(kbase + j) * 8 + (col - 64)];
            v[j] = f2bf(f);
        }
        wfrag[s] = v;
    }
    __syncthreads();

    int w = tid >> 6;       // wave 0..3
    int l = tid & 63;
    int row0 = blockIdx.x * 64;
    int arow = row0 + w * 16 + (l & 15);
    if (arow >= N) arow = N - 1;
    const float* ap = x + (size_t)arow * NFEAT + ((l >> 4) * 8);

    f32x4 acc[5];
#pragma unroll
    for (int nt = 0; nt < 5; ++nt) acc[nt] = (f32x4){0.f, 0.f, 0.f, 0.f};

#pragma unroll
    for (int kt = 0; kt < 8; ++kt) {
        float4 alo = *reinterpret_cast<const float4*>(ap + kt * 32);
        float4 ahi = *reinterpret_cast<const float4*>(ap + kt * 32 + 4);
        bf16x8 af;
        af[0] = f2bf(alo.x); af[1] = f2bf(alo.y); af[2] = f2bf(alo.z); af[3] = f2bf(alo.w);
        af[4] = f2bf(ahi.x); af[5] = f2bf(ahi.y); af[6] = f2bf(ahi.z); af[7] = f2bf(ahi.w);
#pragma unroll
        for (int nt = 0; nt < 5; ++nt) {
            acc[nt] = __builtin_amdgcn_mfma_f32_16x16x32_bf16(
                af, wfrag[(kt * 5 + nt) * 64 + l], acc[nt], 0, 0, 0);
        }
    }

    int cbase = l & 15;
    int rbase = row0 + w * 16 + (l >> 4) * 4;
#pragma unroll
    for (int nt = 0; nt < 4; ++nt) {
#pragma unroll
        for (int r = 0; r < 4; ++r) {
            int row = rbase + r;
            if (row < N) h1b[(size_t)row * 64 + nt * 16 + cbase] = f2bf(acc[nt][r]);
        }
    }
    if (cbase < 8) {
        float bb = fc1b[cbase];
#pragma unroll
        for (int r = 0; r < 4; ++r) {
            int row = rbase + r;
            if (row < N) side1[(size_t)row * 8 + cbase] = acc[4][r] + bb;
        }
    }
}

// ---------------- alpha1: s1b/d1 per node per head ----------------
__global__ __launch_bounds__(256) void alpha1_kernel(const __hip_bfloat16* __restrict__ h1b,
                                                     const float* __restrict__ a1s,
                                                     const float* __restrict__ a1d,
                                                     __hip_bfloat16* __restrict__ s1b,
                                                     float* __restrict__ d1) {
    int wave = threadIdx.x >> 6;
    int lane = threadIdx.x & 63;
    int v = blockIdx.x * 4 + wave;
    if (v >= N) return;
    float hv = __bfloat162float(h1b[(size_t)v * 64 + lane]);
    float sa = hv * a1s[lane];
    float sd = hv * a1d[lane];
#pragma unroll
    for (int off = 1; off < 8; off <<= 1) {
        sa += __shfl_xor(sa, off, 64);
        sd += __shfl_xor(sd, off, 64);
    }
    if ((lane & 7) == 0) {
        s1b[v * 8 + (lane >> 3)] = __float2bfloat16(sa);
        d1[v * 8 + (lane >> 3)] = sd;
    }
}

// ---------------- layer-1 aggregation v4 ----------------------------------------
// Wave per dst node. Transposed attention layout: lane = (head=lane>>3, edge=lane&7)
// => dv identical in both phases, x-broadcast is ds_swizzle with IMMEDIATE pattern,
// den reduce is xor 1/2/4. Fast path (full groups, wave-uniform count) has no
// masks/clamps; single masked tail group. 2-deep ping-pong pipeline retained.
__global__ __launch_bounds__(256) void agg1_kernel(const int* __restrict__ offs,
                                                   const int* __restrict__ csr,
                                                   const unsigned short* __restrict__ h1u,
                                                   const unsigned short* __restrict__ s1u,
                                                   const float* __restrict__ d1,
                                                   const float* __restrict__ side1,
                                                   const float* __restrict__ b1,
                                                   float* __restrict__ hf) {
    int lane = threadIdx.x & 63;
    int v = blockIdx.x * 4 + (threadIdx.x >> 6);
    if (v >= N) return;
    int j  = lane & 7;     // edge slot within group
    int hh = lane >> 3;    // head (both layouts)

    float dv = d1[v * 8 + hh];

    // self loop (channel layout: lane = channel, head hh)
    float e0 = bfu2f(s1u[v * 8 + hh]) + dv;
    e0 = fmaxf(e0, SLOPE * e0);
    float ex0 = __expf(e0);
    float acc = ex0 * bfu2f(h1u[(size_t)v * 64 + lane]);
    float den0 = ex0;
    float den_att = 0.f;

    int beg = offs[v], end = offs[v + 1];
    int deg = end - beg;
    int ngf = deg >> 3;     // full groups (wave-uniform)
    int rem = deg & 7;

    const int* cb = csr + beg;

    unsigned short hA[8], hB[8];
    int s8A = 0, s8B = 0;
    float svA = 0.f, svB = 0.f;

#define LOADH(s8, h)                                                        \
    do {                                                                     \
        int sj0 = __builtin_amdgcn_readlane(s8, 0);                          \
        int sj1 = __builtin_amdgcn_readlane(s8, 1);                          \
        int sj2 = __builtin_amdgcn_readlane(s8, 2);                          \
        int sj3 = __builtin_amdgcn_readlane(s8, 3);                          \
        int sj4 = __builtin_amdgcn_readlane(s8, 4);                          \
        int sj5 = __builtin_amdgcn_readlane(s8, 5);                          \
        int sj6 = __builtin_amdgcn_readlane(s8, 6);                          \
        int sj7 = __builtin_amdgcn_readlane(s8, 7);                          \
        h[0] = h1u[((size_t)sj0 << 6) + lane];                               \
        h[1] = h1u[((size_t)sj1 << 6) + lane];                               \
        h[2] = h1u[((size_t)sj2 << 6) + lane];                               \
        h[3] = h1u[((size_t)sj3 << 6) + lane];                               \
        h[4] = h1u[((size_t)sj4 << 6) + lane];                               \
        h[5] = h1u[((size_t)sj5 << 6) + lane];                               \
        h[6] = h1u[((size_t)sj6 << 6) + lane];                               \
        h[7] = h1u[((size_t)sj7 << 6) + lane];                               \
    } while (0)

#define COMP(sv, h)                                                          \
    do {                                                                     \
        float a = (sv) + dv;                                                 \
        a = fmaxf(a, SLOPE * a);                                             \
        float xv = __expf(a);                                                \
        den_att += xv;                                                       \
        acc += SWZ8(xv, 0x018) * bfu2f(h[0]);                                \
        acc += SWZ8(xv, 0x038) * bfu2f(h[1]);                                \
        acc += SWZ8(xv, 0x058) * bfu2f(h[2]);                                \
        acc += SWZ8(xv, 0x078) * bfu2f(h[3]);                                \
        acc += SWZ8(xv, 0x098) * bfu2f(h[4]);                                \
        acc += SWZ8(xv, 0x0B8) * bfu2f(h[5]);                                \
        acc += SWZ8(xv, 0x0D8) * bfu2f(h[6]);                                \
        acc += SWZ8(xv, 0x0F8) * bfu2f(h[7]);                                \
    } while (0)

    if (ngf > 0) {
        s8A = cb[j];
        svA = bfu2f(s1u[s8A * 8 + hh]);
        LOADH(s8A, hA);
        if (ngf > 1) s8B = cb[8 + j];
    }
    int g = 0;
    for (; g + 1 < ngf; g += 2) {
        svB = bfu2f(s1u[s8B * 8 + hh]);
        LOADH(s8B, hB);
        int s8C = (g + 2 < ngf) ? cb[(g + 2) * 8 + j] : 0;
        COMP(svA, hA);
        s8A = s8C;
        if (g + 2 < ngf) {
            svA = bfu2f(s1u[s8A * 8 + hh]);
            LOADH(s8A, hA);
        }
        int s8D = (g + 3 < ngf) ? cb[(g + 3) * 8 + j] : 0;
        COMP(svB, hB);
        s8B = s8D;
    }
    if (g < ngf) COMP(svA, hA);

    if (rem) {  // masked tail group
        int idx = beg + ngf * 8 + j;
        idx = idx < end ? idx : end - 1;
        int s8 = csr[idx];
        float a = bfu2f(s1u[s8 * 8 + hh]) + dv;
        a = fmaxf(a, SLOPE * a);
        float xv = __expf(a);
        xv = (j < rem) ? xv : 0.f;
        den_att += xv;
        unsigned short ht[8];
        LOADH(s8, ht);
        acc += SWZ8(xv, 0x018) * bfu2f(ht[0]);
        acc += SWZ8(xv, 0x038) * bfu2f(ht[1]);
        acc += SWZ8(xv, 0x058) * bfu2f(ht[2]);
        acc += SWZ8(xv, 0x078) * bfu2f(ht[3]);
        acc += SWZ8(xv, 0x098) * bfu2f(ht[4]);
        acc += SWZ8(xv, 0x0B8) * bfu2f(ht[5]);
        acc += SWZ8(xv, 0x0D8) * bfu2f(ht[6]);
        acc += SWZ8(xv, 0x0F8) * bfu2f(ht[7]);
    }
#undef LOADH
#undef COMP

    // den: sum edge slots within this lane's 8-group
    den_att += __shfl_xor(den_att, 1, 64);
    den_att += __shfl_xor(den_att, 2, 64);
    den_att += __shfl_xor(den_att, 4, 64);
    float den = den0 + den_att;

    float o = acc / den + b1[lane];
    float z = o - L1d * side1[v * 8 + j];   // side channel = c & 7
    hf[(size_t)v * 64 + lane] = z > 0.f ? z : (__expf(z) - 1.f);
}

// ---------------- GEMM2: h2b = bf16(hf @ W2); side2 = hf @ fc2_W + fc2_b --------
__global__ __launch_bounds__(256) void gemm2_kernel(const float* __restrict__ hf,
                                                    const float* __restrict__ W2,
                                                    const float* __restrict__ fc2W,
                                                    const float* __restrict__ fc2b,
                                                    __hip_bfloat16* __restrict__ h2b,
                                                    float* __restrict__ side2) {
    __shared__ float xs[128][65];
    __shared__ float ws[64][33];
    int tid = threadIdx.x;
    int ty = tid >> 3;
    int tx = tid & 7;
    int row0 = blockIdx.x * 128;

    float acc[4][4];
#pragma unroll
    for (int i = 0; i < 4; ++i)
#pragma unroll
        for (int j = 0; j < 4; ++j) acc[i][j] = 0.f;

    int lr = tid >> 4;
    int lj = tid & 15;
#pragma unroll
    for (int it = 0; it < 8; ++it) {
        int r = lr + it * 16;
        int grow = row0 + r;
        if (grow >= N) grow = N - 1;
        float4 vv = *reinterpret_cast<const float4*>(&hf[(size_t)grow * 64 + lj * 4]);
        xs[r][lj * 4 + 0] = vv.x;
        xs[r][lj * 4 + 1] = vv.y;
        xs[r][lj * 4 + 2] = vv.z;
        xs[r][lj * 4 + 3] = vv.w;
    }
    for (int idx = tid; idx < 64 * 32; idx += 256) {
        int k = idx >> 5;
        int c = idx & 31;
        float v = (c < 16) ? W2[(size_t)k * 16 + c] : fc2W[(size_t)k * 16 + (c - 16)];
        ws[k][c] = v;
    }
    __syncthreads();
#pragma unroll 4
    for (int k = 0; k < 64; ++k) {
        float xv[4], wv[4];
#pragma unroll
        for (int i = 0; i < 4; ++i) xv[i] = xs[ty * 4 + i][k];
#pragma unroll
        for (int j = 0; j < 4; ++j) wv[j] = ws[k][tx * 4 + j];
#pragma unroll
        for (int i = 0; i < 4; ++i)
#pragma unroll
            for (int j = 0; j < 4; ++j) acc[i][j] += xv[i] * wv[j];
    }

#pragma unroll
    for (int i = 0; i < 4; ++i) {
        int row = row0 + ty * 4 + i;
        if (row >= N) continue;
#pragma unroll
        for (int j = 0; j < 4; ++j) {
            int c = tx * 4 + j;
            if (c < 16) h2b[(size_t)row * 16 + c] = __float2bfloat16(acc[i][j]);
            else        side2[(size_t)row * 16 + (c - 16)] = acc[i][j] + fc2b[c - 16];
        }
    }
}

// ---------------- alpha2: s2b/d2 per node ----------------
__global__ __launch_bounds__(256) void alpha2_kernel(const __hip_bfloat16* __restrict__ h2b,
                                                     const float* __restrict__ a2s,
                                                     const float* __restrict__ a2d,
                                                     __hip_bfloat16* __restrict__ s2b,
                                                     float* __restrict__ d2) {
    int wave = threadIdx.x >> 6;
    int lane = threadIdx.x & 63;
    int vbase = (blockIdx.x * 4 + wave) * 4;
    int r = lane >> 4;
    int c = lane & 15;
    int v = vbase + r;
    float hv = (v < N) ? __bfloat162float(h2b[(size_t)v * 16 + c]) : 0.f;
    float sa = hv * a2s[c];
    float sd = hv * a2d[c];
#pragma unroll
    for (int off = 1; off < 16; off <<= 1) {
        sa += __shfl_xor(sa, off, 64);
        sd += __shfl_xor(sd, off, 64);
    }
    if (v < N && c == 0) {
        s2b[v] = __float2bfloat16(sa);
        d2[v] = sd;
    }
}

// ---------------- layer-2 aggregation v3 + log_softmax --------------------------
// Wave per dst node. Groups of 4 edges: exp computed once per edge (lanes 0-3 own
// edges), bpermute redistributes x and src to (slot,c) layout; one coalesced 128B
// h-load covers all 4 edges. den accumulated per (slot,c), folded into existing
// cross-slot reduce.
__global__ __launch_bounds__(256) void agg2_kernel(const int* __restrict__ offs,
                                                   const int* __restrict__ csr,
                                                   const unsigned short* __restrict__ h2u,
                                                   const unsigned short* __restrict__ s2u,
                                                   const float* __restrict__ d2,
                                                   const float* __restrict__ side2,
                                                   const float* __restrict__ b2,
                                                   float* __restrict__ out) {
    int lane = threadIdx.x & 63;
    int v = blockIdx.x * 4 + (threadIdx.x >> 6);
    if (v >= N) return;
    int c = lane & 15;
    int slot = lane >> 4;
    int j4 = lane & 3;
    int slotaddr = slot << 2;          // bpermute byte addr of source lane `slot`
    float dv = d2[v];

    float acc = 0.f, den = 0.f;
    if (slot == 0) {
        float e = bfu2f(s2u[v]) + dv;
        e = fmaxf(e, SLOPE * e);
        float ex = __expf(e);
        acc = ex * bfu2f(h2u[(size_t)v * 16 + c]);
        den = ex;
    }
    int beg = offs[v], end = offs[v + 1];
    int deg = end - beg;
    int ngf = deg >> 2;
    int rem = deg & 3;
    const int* cb = csr + beg;

#define COMP2(s4, sv)                                                        \
    do {                                                                     \
        float a = (sv) + dv;                                                 \
        a = fmaxf(a, SLOPE * a);                                             \
        float xv = __expf(a);                                                \
        float xs = __builtin_bit_cast(float,                                 \
            __builtin_amdgcn_ds_bpermute(slotaddr, __builtin_bit_cast(int, xv))); \
        int ss = __builtin_amdgcn_ds_bpermute(slotaddr, (s4));               \
        float hv = bfu2f(h2u[((size_t)ss << 4) + c]);                        \
        acc += xs * hv;                                                      \
        den += xs;                                                           \
    } while (0)

    int s4A = 0, s4B = 0;
    float svA = 0.f, svB = 0.f;
    if (ngf > 0) {
        s4A = cb[j4];
        svA = bfu2f(s2u[s4A]);
        if (ngf > 1) s4B = cb[4 + j4];
    }
    int g = 0;
    for (; g + 1 < ngf; g += 2) {
        svB = bfu2f(s2u[s4B]);
        int s4C = (g + 2 < ngf) ? cb[(g + 2) * 4 + j4] : 0;
        COMP2(s4A, svA);
        s4A = s4C;
        if (g + 2 < ngf) svA = bfu2f(s2u[s4A]);
        int s4D = (g + 3 < ngf) ? cb[(g + 3) * 4 + j4] : 0;
        COMP2(s4B, svB);
        s4B = s4D;
    }
    if (g < ngf) COMP2(s4A, svA);

    if (rem) {  // masked tail group
        int idx = beg + ngf * 4 + j4;
        idx = idx < end ? idx : end - 1;
        int s4 = csr[idx];
        float a = bfu2f(s2u[s4]) + dv;
        a = fmaxf(a, SLOPE * a);
        float xv = __expf(a);
        xv = (j4 < rem) ? xv : 0.f;
        float xs = __builtin_bit_cast(float,
            __builtin_amdgcn_ds_bpermute(slotaddr, __builtin_bit_cast(int, xv)));
        int ss = __builtin_amdgcn_ds_bpermute(slotaddr, s4);
        float hv = bfu2f(h2u[((size_t)ss << 4) + c]);
        acc += xs * hv;
        den += xs;
    }
#undef COMP2

    acc += __shfl_xor(acc, 16, 64);
    acc += __shfl_xor(acc, 32, 64);
    den += __shfl_xor(den, 16, 64);
    den += __shfl_xor(den, 32, 64);

    float o = acc / den + b2[c];
    float z = o - L2d * side2[(size_t)v * 16 + c];

    float m = z;
#pragma unroll
    for (int off = 1; off < 16; off <<= 1) m = fmaxf(m, __shfl_xor(m, off, 64));
    float ex = __expf(z - m);
    float s = ex;
#pragma unroll
    for (int off = 1; off < 16; off <<= 1) s += __shfl_xor(s, off, 64);
    float lsm = z - m - __logf(s);
    if (slot == 0) out[(size_t)v * 16 + c] = lsm;
}

// ---------------- launch ----------------
extern "C" void kernel_launch(void* const* d_in, const int* in_sizes, int n_in,
                              void* d_out, int out_size, void* d_ws, size_t ws_size,
                              hipStream_t stream) {
    const float* x    = (const float*)d_in[0];
    const int*   ei   = (const int*)d_in[1];
    const float* W1   = (const float*)d_in[2];
    const float* a1s  = (const float*)d_in[3];
    const float* a1d  = (const float*)d_in[4];
    const float* b1   = (const float*)d_in[5];
    const float* W2   = (const float*)d_in[6];
    const float* a2s  = (const float*)d_in[7];
    const float* a2d  = (const float*)d_in[8];
    const float* b2   = (const float*)d_in[9];
    const float* fc1W = (const float*)d_in[10];
    const float* fc1b = (const float*)d_in[11];
    const float* fc2W = (const float*)d_in[12];
    const float* fc2b = (const float*)d_in[13];
    float* out = (float*)d_out;

    int*   wsi = (int*)d_ws;
    float* wsf = (float*)d_ws;
    int*   offs   = wsi + W_OFFS;
    int*   csr    = wsi + W_CSR;
    unsigned int* stage = (unsigned int*)(wsi + W_STAGE);
    int*   bhist  = wsi + W_BHIST;
    int*   tot    = wsi + W_TOT;
    int*   bbase  = wsi + W_BBASE;
    __hip_bfloat16* h1b = (__hip_bfloat16*)(wsf + W_H1B);
    __hip_bfloat16* s1b = (__hip_bfloat16*)(wsf + W_S1B);
    float* d1     = wsf + W_D1;
    float* side1  = wsf + W_SIDE1;
    float* hf     = wsf + W_HF;
    __hip_bfloat16* h2b = (__hip_bfloat16*)(wsf + W_H2B);
    float* side2  = wsf + W_SIDE2;
    __hip_bfloat16* s2b = (__hip_bfloat16*)(wsf + W_S2B);
    float* d2     = wsf + W_D2;

    // CSR build (no global atomics)
    p1_hist_kernel<<<NBLK, 256, 0, stream>>>(ei, bhist);
    s1_scan_kernel<<<NBUK, 512, 0, stream>>>(bhist, tot);
    s2_scan_kernel<<<1, 512, 0, stream>>>(tot, bbase, offs);
    p2_stage_kernel<<<NBLK, 256, 0, stream>>>(ei, bhist, bbase, stage);
    p3_fine_kernel<<<NBUK, 256, 0, stream>>>(stage, bbase, offs, csr);

    gemm1_kernel<<<(N + 63) / 64, 256, 0, stream>>>(x, W1, fc1W, fc1b,
                                                    (short*)h1b, side1);
    alpha1_kernel<<<(N + 3) / 4, 256, 0, stream>>>(h1b, a1s, a1d, s1b, d1);
    agg1_kernel<<<(N + 3) / 4, 256, 0, stream>>>(offs, csr,
                                                 (const unsigned short*)h1b,
                                                 (const unsigned short*)s1b,
                                                 d1, side1, b1, hf);

    gemm2_kernel<<<(N + 127) / 128, 256, 0, stream>>>(hf, W2, fc2W, fc2b, h2b, side2);
    alpha2_kernel<<<(N + 15) / 16, 256, 0, stream>>>(h2b, a2s, a2d, s2b, d2);
    agg2_kernel<<<(N + 3) / 4, 256, 0, stream>>>(offs, csr,
                                                 (const unsigned short*)h2b,
                                                 (const unsigned short*)s2b,
                                                 d2, side2, b2, out);
}